// Round 8
// baseline (139.803 us; speedup 1.0000x reference)
//
#include <hip/hip_runtime.h>
#include <hip/hip_bf16.h>
#include <cstdint>
#include <cstddef>

// Problem constants
#define B_ 8
#define S_ 2048
#define D_ 1024
#define RFAC 32.0f
#define ALPHA 0.2f
#define BETA 0.1f
#define GAMMA 0.1f
// EMA truncation window: 0.8^32 ~ 8e-4 (threshold 0.108)
#define KW 32
#define TB 64
#define PF_ 8   // ema prefetch pipeline depth (static ring, fully unrolled)

typedef float f32x4_t __attribute__((ext_vector_type(4)));
typedef short bf16x8_t __attribute__((ext_vector_type(8)));

__device__ __forceinline__ unsigned short f2bf(float f) {
    unsigned u = __float_as_uint(f);
    u = (u + 0x7fffu + ((u >> 16) & 1u)) >> 16;
    return (unsigned short)u;
}
__device__ __forceinline__ float bf2f(unsigned short h) {
    return __uint_as_float(((unsigned)h) << 16);
}

// ---------------------------------------------------------------------------
// Kernel 1: W -> bf16 convert.
__global__ __launch_bounds__(256) void wconv_k(const float* __restrict__ W,
                                               unsigned short* __restrict__ Wb) {
    int i = blockIdx.x * 256 + threadIdx.x;
    float4 w = ((const float4*)W)[i];
    ushort4 o;
    o.x = f2bf(w.x); o.y = f2bf(w.y); o.z = f2bf(w.z); o.w = f2bf(w.w);
    ((ushort4*)Wb)[i] = o;
}

// ---------------------------------------------------------------------------
// Kernel 2: FULLY FUSED norm + windowed EMA + coef (single pass over q,k,vv
// = the 224MB traffic minimum; R7 paid 2x for q,k).
// Block = (b, 64-step chunk), 256 thr x 4 d's. Per t: block-reduce row
// sumsq (wave butterfly -> 1 LDS slot, double-slotted, 1 barrier) gives the
// norm scalars just-in-time for the EMA update; uu/sd reduce stays
// butterfly-only with per-t LDS slots finished after the loop.
__global__ __launch_bounds__(256) void ema_fused_k(const float* __restrict__ q,
                                                   const float* __restrict__ kk,
                                                   const float* __restrict__ vv,
                                                   unsigned short* __restrict__ Ub,
                                                   float* __restrict__ coef) {
    __shared__ float smn[2][8];    // [t&1][wave*2 + {q,k}] norm partials
    __shared__ float sm2[TB * 8];  // [t][wave*2 + {uu,sd}]
    const int chunks = S_ / TB;
    int b  = blockIdx.x / chunks;
    int t0 = (blockIdx.x % chunks) * TB;
    int ts = t0 - KW; if (ts < 0) ts = 0;
    int tid = threadIdx.x;
    int lane = tid & 63, wave = tid >> 6;
    size_t bbase = (size_t)b * S_ * D_ + tid * 4;
    const float* qp = q + bbase;
    const float* kp = kk + bbase;
    const float* vp = vv + bbase;
    unsigned short* up = Ub + bbase;

    float4 pq[PF_], pk[PF_], pv[PF_];
#pragma unroll
    for (int j = 0; j < PF_; ++j) {
        size_t o = (size_t)(ts + j) * D_;
        pq[j] = *(const float4*)(qp + o);
        pk[j] = *(const float4*)(kp + o);
        if (ts + j >= t0) pv[j] = *(const float4*)(vp + o);
    }
    float u0 = 0.f, u1 = 0.f, u2 = 0.f, u3 = 0.f;
    float v0 = 0.f, v1 = 0.f, v2 = 0.f, v3 = 0.f;
    const float om = 1.f - ALPHA;
    const int NI = t0 + TB - ts;       // 64 (chunk 0) or 96; both % 8 == 0
    const int tend = t0 + TB;
    for (int g = 0; g < NI; g += PF_) {
#pragma unroll
        for (int j = 0; j < PF_; ++j) {
            int t = ts + g + j;
            int slot = t & 1;
            // --- block-wide row-norm reduce (just-in-time) ---
            float sqq = pq[j].x * pq[j].x + pq[j].y * pq[j].y
                      + pq[j].z * pq[j].z + pq[j].w * pq[j].w;
            float sqk = pk[j].x * pk[j].x + pk[j].y * pk[j].y
                      + pk[j].z * pk[j].z + pk[j].w * pk[j].w;
#pragma unroll
            for (int off = 32; off > 0; off >>= 1) {
                sqq += __shfl_xor(sqq, off, 64);
                sqk += __shfl_xor(sqk, off, 64);
            }
            if (lane == 0) {
                smn[slot][wave * 2 + 0] = sqq;
                smn[slot][wave * 2 + 1] = sqk;
            }
            __syncthreads();
            float nq = smn[slot][0] + smn[slot][2] + smn[slot][4] + smn[slot][6];
            float nk = smn[slot][1] + smn[slot][3] + smn[slot][5] + smn[slot][7];
            float aq = ALPHA / (sqrtf(nq) + 1e-6f);
            float ak = ALPHA / (sqrtf(nk) + 1e-6f);
            // --- EMA update ---
            u0 = om * u0 + aq * pq[j].x; u1 = om * u1 + aq * pq[j].y;
            u2 = om * u2 + aq * pq[j].z; u3 = om * u3 + aq * pq[j].w;
            v0 = om * v0 + ak * pk[j].x; v1 = om * v1 + ak * pk[j].y;
            v2 = om * v2 + ak * pk[j].z; v3 = om * v3 + ak * pk[j].w;
            if (t >= t0) {               // wave-uniform branch
                float uu = u0 * u0 + u1 * u1 + u2 * u2 + u3 * u3;
                float sd = v0 * pv[j].x + v1 * pv[j].y + v2 * pv[j].z + v3 * pv[j].w;
#pragma unroll
                for (int off = 32; off > 0; off >>= 1) {
                    uu += __shfl_xor(uu, off, 64);
                    sd += __shfl_xor(sd, off, 64);
                }
                if (lane == 0) {
                    sm2[(t - t0) * 8 + wave * 2 + 0] = uu;
                    sm2[(t - t0) * 8 + wave * 2 + 1] = sd;
                }
                ushort4 us;
                us.x = f2bf(u0); us.y = f2bf(u1); us.z = f2bf(u2); us.w = f2bf(u3);
                *(ushort4*)(up + (size_t)t * D_) = us;
            }
            // prefetch t+PF_ into slot j (clamped; duplicate loads harmless)
            int tf = t + PF_;
            int tc = tf < tend ? tf : tend - 1;
            size_t o2 = (size_t)tc * D_;
            pq[j] = *(const float4*)(qp + o2);
            pk[j] = *(const float4*)(kp + o2);
            if (tf >= t0) pv[j] = *(const float4*)(vp + o2);
        }
    }
    __syncthreads();
    if (tid < TB) {
        float uu = sm2[tid * 8 + 0] + sm2[tid * 8 + 2] + sm2[tid * 8 + 4] + sm2[tid * 8 + 6];
        float sd = sm2[tid * 8 + 1] + sm2[tid * 8 + 3] + sm2[tid * 8 + 5] + sm2[tid * 8 + 7];
        float nrm = RFAC * fabsf(sd) * sqrtf(uu);
        float n = fmaxf(nrm, 1e-6f);
        coef[b * S_ + t0 + tid] = GAMMA * RFAC * sd / (1.f + BETA * (n - 1.f));
    }
}

// ---------------------------------------------------------------------------
// Kernel 3: out[m,n] = x[m,n] + coef[m] * sum_d U[m,d] * W[n,d]
// 128x128 tile, BK=64, 4 waves (2x2), double-buffered 64KB LDS -> 2
// blocks/CU, grid 1024 = 4 staggered generations: one block's x/out
// epilogue overlaps its CU-mate's K-loop (R7 lesson: grid==CU-count made
// the epilogue a chip-wide serial phase). Counted vmcnt 2-deep pipeline,
// no drain0 in steady state; XOR chunk swizzle both-sides.
#define BM 128
#define BN 128
#define BK 64
#define NT (D_ / BK)   // 16 K-tiles

__global__ __launch_bounds__(256) void gemm_k(const unsigned short* __restrict__ A,   // M x K bf16
                                              const unsigned short* __restrict__ Bw,  // N x K bf16
                                              const float* __restrict__ coef,
                                              const float* __restrict__ x,
                                              float* __restrict__ out) {
    const int N = D_, K = D_;
    __shared__ unsigned short lds[2 * 2 * BM * BK];   // [buf][A|B], 64 KiB
    int bid = blockIdx.x;
    int swz = (bid & 7) * 128 + (bid >> 3);  // 1024 % 8 == 0: bijective XCD remap
    int tm = swz >> 3, tn = swz & 7;         // 128 M-tiles, 8 N-tiles
    int m0 = tm * BM, n0 = tn * BN;
    int tid = threadIdx.x;
    int lane = tid & 63;
    int wid = tid >> 6;
    int wr = wid >> 1, wc = wid & 1;         // 2x2 wave grid; wave tile 64x64
    int lr = lane & 15, lg = lane >> 4;

    f32x4_t acc[4][4];
#pragma unroll
    for (int i = 0; i < 4; ++i)
#pragma unroll
        for (int j = 0; j < 4; ++j)
            acc[i][j] = (f32x4_t){0.f, 0.f, 0.f, 0.f};

    // stage one matrix (128 rows x 8 chunks of 16B = 1024 chunks / 256 thr)
#define STAGE_MAT(buf, kt, isB)                                                       \
    {                                                                                 \
        const unsigned short* Gp =                                                    \
            ((isB) ? Bw + (size_t)n0 * K : A + (size_t)m0 * K) + (size_t)(kt) * BK;   \
        char* Lp = (char*)lds + (buf) * 32768 + (isB) * 16384;                        \
        _Pragma("unroll")                                                             \
        for (int i = 0; i < 4; ++i) {                                                 \
            int c = i * 256 + tid;                                                    \
            int row = c >> 3, cl = c & 7;                                             \
            int gc = cl ^ (row & 7);          /* pre-swizzled global chunk */         \
            __builtin_amdgcn_global_load_lds(                                         \
                (const __attribute__((address_space(1))) void*)(Gp + (size_t)row * K + gc * 8), \
                (__attribute__((address_space(3))) void*)(Lp + c * 16), 16, 0, 0);    \
        }                                                                             \
    }
#define STAGE_TILE(buf, kt) STAGE_MAT(buf, kt, 0) STAGE_MAT(buf, kt, 1)

    // prologue: 2-deep — tiles 0 and 1 both in flight (8 insts/thread each)
    STAGE_TILE(0, 0);
    STAGE_TILE(1, 1);

    for (int t = 0; t < NT; ++t) {
        // steady state: wait only until tile t's 8 loads landed (t+1's and
        // t+2's stay in flight). Last tile: full drain (only 8 outstanding).
        if (t == NT - 1) asm volatile("s_waitcnt vmcnt(0)" ::: "memory");
        else             asm volatile("s_waitcnt vmcnt(8)" ::: "memory");
        __builtin_amdgcn_s_barrier();        // staged data visible block-wide
        const unsigned short* La = lds + (t & 1) * 16384;
        const unsigned short* Lb = La + 8192;
        bf16x8_t af[4][2], bf[4][2];
#pragma unroll
        for (int kkk = 0; kkk < 2; ++kkk) {
#pragma unroll
            for (int mi = 0; mi < 4; ++mi) {
                int row = wr * 64 + mi * 16 + lr;
                int ch = (kkk * 4 + lg) ^ (row & 7);
                af[mi][kkk] = *(const bf16x8_t*)(La + (row * 8 + ch) * 8);
            }
#pragma unroll
            for (int ni = 0; ni < 4; ++ni) {
                int row = wc * 64 + ni * 16 + lr;
                int ch = (kkk * 4 + lg) ^ (row & 7);
                bf[ni][kkk] = *(const bf16x8_t*)(Lb + (row * 8 + ch) * 8);
            }
        }
        asm volatile("s_waitcnt lgkmcnt(0)" ::: "memory");
        __builtin_amdgcn_sched_barrier(0);
        __builtin_amdgcn_s_setprio(1);
#pragma unroll
        for (int kkk = 0; kkk < 2; ++kkk)
#pragma unroll
            for (int mi = 0; mi < 4; ++mi)
#pragma unroll
                for (int ni = 0; ni < 4; ++ni)
                    acc[mi][ni] = __builtin_amdgcn_mfma_f32_16x16x32_bf16(
                        af[mi][kkk], bf[ni][kkk], acc[mi][ni], 0, 0, 0);
        __builtin_amdgcn_s_setprio(0);
        __builtin_amdgcn_s_barrier();        // all waves done reading buf t&1
        if (t + 2 < NT) { STAGE_TILE((t & 1), t + 2); }   // into the freed buffer
    }
#undef STAGE_TILE
#undef STAGE_MAT

    // Epilogue: C/D layout col = lane&15, row = (lane>>4)*4 + reg
#pragma unroll
    for (int mi = 0; mi < 4; ++mi) {
#pragma unroll
        for (int i = 0; i < 4; ++i) {
            int m = m0 + wr * 64 + mi * 16 + lg * 4 + i;
            float cf = coef[m];
#pragma unroll
            for (int ni = 0; ni < 4; ++ni) {
                int n = n0 + wc * 64 + ni * 16 + lr;
                size_t idx = (size_t)m * N + n;
                out[idx] = x[idx] + cf * acc[mi][ni][i];
            }
        }
    }
}

// ---------------------------------------------------------------------------
extern "C" void kernel_launch(void* const* d_in, const int* in_sizes, int n_in,
                              void* d_out, int out_size, void* d_ws, size_t ws_size,
                              hipStream_t stream) {
    const float* x  = (const float*)d_in[0];
    const float* q  = (const float*)d_in[1];
    const float* k  = (const float*)d_in[2];
    const float* vv = (const float*)d_in[3];
    const float* W  = (const float*)d_in[4];
    float* out = (float*)d_out;

    const size_t M = (size_t)B_ * S_;           // 16384
    char* ws = (char*)d_ws;
    unsigned short* Ub = (unsigned short*)ws;                      // 32MB
    unsigned short* Wb = (unsigned short*)(ws + M * D_ * 2);       // 2MB
    float* coef = (float*)(ws + M * D_ * 2 + (size_t)D_ * D_ * 2);
    size_t needed = M * D_ * 2 + (size_t)D_ * D_ * 2 + M * 4;
    if (ws_size < needed) return;  // fail visibly (output stays poisoned)

    wconv_k<<<dim3((D_ * D_) / 1024), dim3(256), 0, stream>>>(W, Wb);
    ema_fused_k<<<dim3(B_ * (S_ / TB)), dim3(256), 0, stream>>>(q, k, vv, Ub, coef);
    gemm_k<<<dim3((M / BM) * (D_ / BN)), dim3(256), 0, stream>>>(Ub, Wb, coef, x, out);
}

// Round 9
// 138.950 us; speedup vs baseline: 1.0061x; 1.0061x over previous
//
#include <hip/hip_runtime.h>
#include <hip/hip_bf16.h>
#include <cstdint>
#include <cstddef>

// Problem constants
#define B_ 8
#define S_ 2048
#define D_ 1024
#define RFAC 32.0f
#define ALPHA 0.2f
#define BETA 0.1f
#define GAMMA 0.1f
// EMA truncation window: 0.8^32 ~ 8e-4 (threshold 0.108)
#define KW 32
#define TB 64
#define PF_ 8   // ema prefetch pipeline depth (static ring, fully unrolled)

typedef float f32x4_t __attribute__((ext_vector_type(4)));
typedef short bf16x8_t __attribute__((ext_vector_type(8)));

__device__ __forceinline__ unsigned short f2bf(float f) {
    unsigned u = __float_as_uint(f);
    u = (u + 0x7fffu + ((u >> 16) & 1u)) >> 16;
    return (unsigned short)u;
}
__device__ __forceinline__ float bf2f(unsigned short h) {
    return __uint_as_float(((unsigned)h) << 16);
}

// ---------------------------------------------------------------------------
// Kernel 1: W -> bf16 convert.
__global__ __launch_bounds__(256) void wconv_k(const float* __restrict__ W,
                                               unsigned short* __restrict__ Wb) {
    int i = blockIdx.x * 256 + threadIdx.x;
    float4 w = ((const float4*)W)[i];
    ushort4 o;
    o.x = f2bf(w.x); o.y = f2bf(w.y); o.z = f2bf(w.z); o.w = f2bf(w.w);
    ((ushort4*)Wb)[i] = o;
}

// ---------------------------------------------------------------------------
// Kernel 2: FULLY FUSED norm + windowed EMA + coef, single pass over q,k,vv.
// R8 lesson: per-t __syncthreads() emits s_waitcnt vmcnt(0), draining the
// 8-deep prefetch ring every step (100us, 1.3TB/s). The cross-wave norm
// reduce only depends on LDS: ds_write -> lgkmcnt(0) -> RAW s_barrier keeps
// the global prefetch loads in flight across the barrier (T4 principle).
__global__ __launch_bounds__(256) void ema_fused_k(const float* __restrict__ q,
                                                   const float* __restrict__ kk,
                                                   const float* __restrict__ vv,
                                                   unsigned short* __restrict__ Ub,
                                                   float* __restrict__ coef) {
    __shared__ float smn[2][8];    // [t&1][wave*2 + {q,k}] norm partials
    __shared__ float sm2[TB * 8];  // [t][wave*2 + {uu,sd}]
    const int chunks = S_ / TB;
    int b  = blockIdx.x / chunks;
    int t0 = (blockIdx.x % chunks) * TB;
    int ts = t0 - KW; if (ts < 0) ts = 0;
    int tid = threadIdx.x;
    int lane = tid & 63, wave = tid >> 6;
    size_t bbase = (size_t)b * S_ * D_ + tid * 4;
    const float* qp = q + bbase;
    const float* kp = kk + bbase;
    const float* vp = vv + bbase;
    unsigned short* up = Ub + bbase;

    float4 pq[PF_], pk[PF_], pv[PF_];
#pragma unroll
    for (int j = 0; j < PF_; ++j) {
        size_t o = (size_t)(ts + j) * D_;
        pq[j] = *(const float4*)(qp + o);
        pk[j] = *(const float4*)(kp + o);
        if (ts + j >= t0) pv[j] = *(const float4*)(vp + o);
    }
    float u0 = 0.f, u1 = 0.f, u2 = 0.f, u3 = 0.f;
    float v0 = 0.f, v1 = 0.f, v2 = 0.f, v3 = 0.f;
    const float om = 1.f - ALPHA;
    const int NI = t0 + TB - ts;       // 64 (chunk 0) or 96; both % 8 == 0
    const int tend = t0 + TB;
    for (int g = 0; g < NI; g += PF_) {
#pragma unroll
        for (int j = 0; j < PF_; ++j) {
            int t = ts + g + j;
            int slot = t & 1;
            // --- block-wide row-norm reduce (LDS-only sync; vmem stays hot) ---
            float sqq = pq[j].x * pq[j].x + pq[j].y * pq[j].y
                      + pq[j].z * pq[j].z + pq[j].w * pq[j].w;
            float sqk = pk[j].x * pk[j].x + pk[j].y * pk[j].y
                      + pk[j].z * pk[j].z + pk[j].w * pk[j].w;
#pragma unroll
            for (int off = 32; off > 0; off >>= 1) {
                sqq += __shfl_xor(sqq, off, 64);
                sqk += __shfl_xor(sqk, off, 64);
            }
            if (lane == 0) {
                smn[slot][wave * 2 + 0] = sqq;
                smn[slot][wave * 2 + 1] = sqk;
            }
            // LDS-only barrier: do NOT drain vmcnt (prefetch ring stays live).
            asm volatile("s_waitcnt lgkmcnt(0)" ::: "memory");
            __builtin_amdgcn_s_barrier();
            asm volatile("" ::: "memory");   // fence: no hoisting reads above
            float nq = smn[slot][0] + smn[slot][2] + smn[slot][4] + smn[slot][6];
            float nk = smn[slot][1] + smn[slot][3] + smn[slot][5] + smn[slot][7];
            float aq = ALPHA / (sqrtf(nq) + 1e-6f);
            float ak = ALPHA / (sqrtf(nk) + 1e-6f);
            // --- EMA update ---
            u0 = om * u0 + aq * pq[j].x; u1 = om * u1 + aq * pq[j].y;
            u2 = om * u2 + aq * pq[j].z; u3 = om * u3 + aq * pq[j].w;
            v0 = om * v0 + ak * pk[j].x; v1 = om * v1 + ak * pk[j].y;
            v2 = om * v2 + ak * pk[j].z; v3 = om * v3 + ak * pk[j].w;
            if (t >= t0) {               // wave-uniform branch
                float uu = u0 * u0 + u1 * u1 + u2 * u2 + u3 * u3;
                float sd = v0 * pv[j].x + v1 * pv[j].y + v2 * pv[j].z + v3 * pv[j].w;
#pragma unroll
                for (int off = 32; off > 0; off >>= 1) {
                    uu += __shfl_xor(uu, off, 64);
                    sd += __shfl_xor(sd, off, 64);
                }
                if (lane == 0) {
                    sm2[(t - t0) * 8 + wave * 2 + 0] = uu;
                    sm2[(t - t0) * 8 + wave * 2 + 1] = sd;
                }
                ushort4 us;
                us.x = f2bf(u0); us.y = f2bf(u1); us.z = f2bf(u2); us.w = f2bf(u3);
                *(ushort4*)(up + (size_t)t * D_) = us;
            }
            // prefetch t+PF_ into slot j (clamped; duplicate loads harmless)
            int tf = t + PF_;
            int tc = tf < tend ? tf : tend - 1;
            size_t o2 = (size_t)tc * D_;
            pq[j] = *(const float4*)(qp + o2);
            pk[j] = *(const float4*)(kp + o2);
            if (tf >= t0) pv[j] = *(const float4*)(vp + o2);
        }
    }
    __syncthreads();
    if (tid < TB) {
        float uu = sm2[tid * 8 + 0] + sm2[tid * 8 + 2] + sm2[tid * 8 + 4] + sm2[tid * 8 + 6];
        float sd = sm2[tid * 8 + 1] + sm2[tid * 8 + 3] + sm2[tid * 8 + 5] + sm2[tid * 8 + 7];
        float nrm = RFAC * fabsf(sd) * sqrtf(uu);
        float n = fmaxf(nrm, 1e-6f);
        coef[b * S_ + t0 + tid] = GAMMA * RFAC * sd / (1.f + BETA * (n - 1.f));
    }
}

// ---------------------------------------------------------------------------
// Kernel 3: out[m,n] = x[m,n] + coef[m] * sum_d U[m,d] * W[n,d]
// 128x128 tile, BK=64, 4 waves (2x2), double-buffered 64KB LDS -> 2
// blocks/CU, grid 1024 (4 staggered generations: epilogue overlaps CU-mate's
// K-loop). Counted vmcnt 2-deep pipeline, no drain0 in steady state; XOR
// chunk swizzle both-sides. Measured ~37us in R8 — unchanged.
#define BM 128
#define BN 128
#define BK 64
#define NT (D_ / BK)   // 16 K-tiles

__global__ __launch_bounds__(256) void gemm_k(const unsigned short* __restrict__ A,   // M x K bf16
                                              const unsigned short* __restrict__ Bw,  // N x K bf16
                                              const float* __restrict__ coef,
                                              const float* __restrict__ x,
                                              float* __restrict__ out) {
    const int N = D_, K = D_;
    __shared__ unsigned short lds[2 * 2 * BM * BK];   // [buf][A|B], 64 KiB
    int bid = blockIdx.x;
    int swz = (bid & 7) * 128 + (bid >> 3);  // 1024 % 8 == 0: bijective XCD remap
    int tm = swz >> 3, tn = swz & 7;         // 128 M-tiles, 8 N-tiles
    int m0 = tm * BM, n0 = tn * BN;
    int tid = threadIdx.x;
    int lane = tid & 63;
    int wid = tid >> 6;
    int wr = wid >> 1, wc = wid & 1;         // 2x2 wave grid; wave tile 64x64
    int lr = lane & 15, lg = lane >> 4;

    f32x4_t acc[4][4];
#pragma unroll
    for (int i = 0; i < 4; ++i)
#pragma unroll
        for (int j = 0; j < 4; ++j)
            acc[i][j] = (f32x4_t){0.f, 0.f, 0.f, 0.f};

    // stage one matrix (128 rows x 8 chunks of 16B = 1024 chunks / 256 thr)
#define STAGE_MAT(buf, kt, isB)                                                       \
    {                                                                                 \
        const unsigned short* Gp =                                                    \
            ((isB) ? Bw + (size_t)n0 * K : A + (size_t)m0 * K) + (size_t)(kt) * BK;   \
        char* Lp = (char*)lds + (buf) * 32768 + (isB) * 16384;                        \
        _Pragma("unroll")                                                             \
        for (int i = 0; i < 4; ++i) {                                                 \
            int c = i * 256 + tid;                                                    \
            int row = c >> 3, cl = c & 7;                                             \
            int gc = cl ^ (row & 7);          /* pre-swizzled global chunk */         \
            __builtin_amdgcn_global_load_lds(                                         \
                (const __attribute__((address_space(1))) void*)(Gp + (size_t)row * K + gc * 8), \
                (__attribute__((address_space(3))) void*)(Lp + c * 16), 16, 0, 0);    \
        }                                                                             \
    }
#define STAGE_TILE(buf, kt) STAGE_MAT(buf, kt, 0) STAGE_MAT(buf, kt, 1)

    // prologue: 2-deep — tiles 0 and 1 both in flight (8 insts/thread each)
    STAGE_TILE(0, 0);
    STAGE_TILE(1, 1);

    for (int t = 0; t < NT; ++t) {
        // steady state: wait only until tile t's 8 loads landed (t+1's and
        // t+2's stay in flight). Last tile: full drain (only 8 outstanding).
        if (t == NT - 1) asm volatile("s_waitcnt vmcnt(0)" ::: "memory");
        else             asm volatile("s_waitcnt vmcnt(8)" ::: "memory");
        __builtin_amdgcn_s_barrier();        // staged data visible block-wide
        const unsigned short* La = lds + (t & 1) * 16384;
        const unsigned short* Lb = La + 8192;
        bf16x8_t af[4][2], bf[4][2];
#pragma unroll
        for (int kkk = 0; kkk < 2; ++kkk) {
#pragma unroll
            for (int mi = 0; mi < 4; ++mi) {
                int row = wr * 64 + mi * 16 + lr;
                int ch = (kkk * 4 + lg) ^ (row & 7);
                af[mi][kkk] = *(const bf16x8_t*)(La + (row * 8 + ch) * 8);
            }
#pragma unroll
            for (int ni = 0; ni < 4; ++ni) {
                int row = wc * 64 + ni * 16 + lr;
                int ch = (kkk * 4 + lg) ^ (row & 7);
                bf[ni][kkk] = *(const bf16x8_t*)(Lb + (row * 8 + ch) * 8);
            }
        }
        asm volatile("s_waitcnt lgkmcnt(0)" ::: "memory");
        __builtin_amdgcn_sched_barrier(0);
        __builtin_amdgcn_s_setprio(1);
#pragma unroll
        for (int kkk = 0; kkk < 2; ++kkk)
#pragma unroll
            for (int mi = 0; mi < 4; ++mi)
#pragma unroll
                for (int ni = 0; ni < 4; ++ni)
                    acc[mi][ni] = __builtin_amdgcn_mfma_f32_16x16x32_bf16(
                        af[mi][kkk], bf[ni][kkk], acc[mi][ni], 0, 0, 0);
        __builtin_amdgcn_s_setprio(0);
        __builtin_amdgcn_s_barrier();        // all waves done reading buf t&1
        if (t + 2 < NT) { STAGE_TILE((t & 1), t + 2); }   // into the freed buffer
    }
#undef STAGE_TILE
#undef STAGE_MAT

    // Epilogue: C/D layout col = lane&15, row = (lane>>4)*4 + reg
#pragma unroll
    for (int mi = 0; mi < 4; ++mi) {
#pragma unroll
        for (int i = 0; i < 4; ++i) {
            int m = m0 + wr * 64 + mi * 16 + lg * 4 + i;
            float cf = coef[m];
#pragma unroll
            for (int ni = 0; ni < 4; ++ni) {
                int n = n0 + wc * 64 + ni * 16 + lr;
                size_t idx = (size_t)m * N + n;
                out[idx] = x[idx] + cf * acc[mi][ni][i];
            }
        }
    }
}

// ---------------------------------------------------------------------------
extern "C" void kernel_launch(void* const* d_in, const int* in_sizes, int n_in,
                              void* d_out, int out_size, void* d_ws, size_t ws_size,
                              hipStream_t stream) {
    const float* x  = (const float*)d_in[0];
    const float* q  = (const float*)d_in[1];
    const float* k  = (const float*)d_in[2];
    const float* vv = (const float*)d_in[3];
    const float* W  = (const float*)d_in[4];
    float* out = (float*)d_out;

    const size_t M = (size_t)B_ * S_;           // 16384
    char* ws = (char*)d_ws;
    unsigned short* Ub = (unsigned short*)ws;                      // 32MB
    unsigned short* Wb = (unsigned short*)(ws + M * D_ * 2);       // 2MB
    float* coef = (float*)(ws + M * D_ * 2 + (size_t)D_ * D_ * 2);
    size_t needed = M * D_ * 2 + (size_t)D_ * D_ * 2 + M * 4;
    if (ws_size < needed) return;  // fail visibly (output stays poisoned)

    wconv_k<<<dim3((D_ * D_) / 1024), dim3(256), 0, stream>>>(W, Wb);
    ema_fused_k<<<dim3(B_ * (S_ / TB)), dim3(256), 0, stream>>>(q, k, vv, Ub, coef);
    gemm_k<<<dim3((M / BM) * (D_ / BN)), dim3(256), 0, stream>>>(Ub, Wb, coef, x, out);
}

// Round 10
// 138.366 us; speedup vs baseline: 1.0104x; 1.0042x over previous
//
#include <hip/hip_runtime.h>
#include <hip/hip_bf16.h>
#include <cstdint>
#include <cstddef>

// Problem constants
#define B_ 8
#define S_ 2048
#define D_ 1024
#define RFAC 32.0f
#define ALPHA 0.2f
#define BETA 0.1f
#define GAMMA 0.1f
// EMA truncation window: 0.8^32 ~ 8e-4 (threshold 0.108)
#define KW 32
#define TB 64
#define PF_ 8   // ema prefetch pipeline depth (static ring, fully unrolled)
#define NS 4    // norm-reduce produce-ahead distance (< PF_)

typedef float f32x4_t __attribute__((ext_vector_type(4)));
typedef short bf16x8_t __attribute__((ext_vector_type(8)));

__device__ __forceinline__ unsigned short f2bf(float f) {
    unsigned u = __float_as_uint(f);
    u = (u + 0x7fffu + ((u >> 16) & 1u)) >> 16;
    return (unsigned short)u;
}

// ---------------------------------------------------------------------------
// Kernel 1: W -> bf16 convert.
__global__ __launch_bounds__(256) void wconv_k(const float* __restrict__ W,
                                               unsigned short* __restrict__ Wb) {
    int i = blockIdx.x * 256 + threadIdx.x;
    float4 w = ((const float4*)W)[i];
    ushort4 o;
    o.x = f2bf(w.x); o.y = f2bf(w.y); o.z = f2bf(w.z); o.w = f2bf(w.w);
    ((ushort4*)Wb)[i] = o;
}

// ---------------------------------------------------------------------------
// Kernel 2: fused norm+EMA+coef with PIPELINED REDUCTIONS (R9 lesson: the
// per-t dep chain [butterfly->write->drain->barrier->read->sqrt->EMA->
// butterfly2] at 1 wave/SIMD was the 100us cost, not traffic).
//  - norm partials for t+NS are butterflied+written at iteration t (data
//    arrived NS iterations ago in the prefetch ring) -> consumption at t
//    reads scalars written NS barriers ago: no inline wait.
//  - uu/sd: NO in-loop shuffle; per-thread partials ds_write_b64'd into
//    pp[64][256][2] (128KB LDS), reduced post-loop (coef written there).
//  - one raw lgkmcnt(0)+s_barrier per t; vmcnt NEVER drained in-loop.
__global__ __launch_bounds__(256) void ema_fused_k(const float* __restrict__ q,
                                                   const float* __restrict__ kk,
                                                   const float* __restrict__ vv,
                                                   unsigned short* __restrict__ Ub,
                                                   float* __restrict__ coef) {
    __shared__ float smn[8][8];        // [t&7][wave*2+{q,k}] norm partials
    __shared__ float pp[TB][256][2];   // [t-t0][tid][{uu,sd}]  128 KB
    const int chunks = S_ / TB;
    int b  = blockIdx.x / chunks;
    int t0 = (blockIdx.x % chunks) * TB;
    int ts = t0 - KW; if (ts < 0) ts = 0;
    int tid = threadIdx.x;
    int lane = tid & 63, wave = tid >> 6;
    size_t bbase = (size_t)b * S_ * D_ + tid * 4;
    const float* qp = q + bbase;
    const float* kp = kk + bbase;
    const float* vp = vv + bbase;
    unsigned short* up = Ub + bbase;
    const int tend = t0 + TB;

    float4 pq[PF_], pk[PF_], pv[PF_];
#pragma unroll
    for (int j = 0; j < PF_; ++j) {
        size_t o = (size_t)(ts + j) * D_;
        pq[j] = *(const float4*)(qp + o);
        pk[j] = *(const float4*)(kp + o);
        if (ts + j >= t0) pv[j] = *(const float4*)(vp + o);
    }
    // prologue: produce norm partials for times ts..ts+NS-1
#pragma unroll
    for (int j = 0; j < NS; ++j) {
        float sqq = pq[j].x*pq[j].x + pq[j].y*pq[j].y + pq[j].z*pq[j].z + pq[j].w*pq[j].w;
        float sqk = pk[j].x*pk[j].x + pk[j].y*pk[j].y + pk[j].z*pk[j].z + pk[j].w*pk[j].w;
#pragma unroll
        for (int off = 32; off > 0; off >>= 1) {
            sqq += __shfl_xor(sqq, off, 64);
            sqk += __shfl_xor(sqk, off, 64);
        }
        if (lane == 0) {
            smn[(ts + j) & 7][wave * 2 + 0] = sqq;
            smn[(ts + j) & 7][wave * 2 + 1] = sqk;
        }
    }
    __syncthreads();   // one-time full drain (prologue only)

    float u0=0.f,u1=0.f,u2=0.f,u3=0.f,v0=0.f,v1=0.f,v2=0.f,v3=0.f;
    const float om = 1.f - ALPHA;
    const int NI = tend - ts;          // 64 or 96, both % PF_ == 0
    for (int g = 0; g < NI; g += PF_) {
#pragma unroll
        for (int j = 0; j < PF_; ++j) {
            int t = ts + g + j;
            // one LDS-only barrier per t (vm loads stay in flight)
            asm volatile("s_waitcnt lgkmcnt(0)" ::: "memory");
            __builtin_amdgcn_s_barrier();
            // ---- produce norm partials for t+NS (slot (j+NS)&7; its data
            //      arrived NS iterations ago). Off the consume critical path:
            //      result needed only NS barriers later. ----
            int tN = t + NS;
            if (tN < tend) {                      // wave-uniform guard
                int sN = (j + NS) & 7;            // compile-time (j unrolled)
                float4 aN = pq[sN], bN = pk[sN];
                float sqq = aN.x*aN.x + aN.y*aN.y + aN.z*aN.z + aN.w*aN.w;
                float sqk = bN.x*bN.x + bN.y*bN.y + bN.z*bN.z + bN.w*bN.w;
#pragma unroll
                for (int off = 32; off > 0; off >>= 1) {
                    sqq += __shfl_xor(sqq, off, 64);
                    sqk += __shfl_xor(sqk, off, 64);
                }
                if (lane == 0) {
                    smn[tN & 7][wave * 2 + 0] = sqq;
                    smn[tN & 7][wave * 2 + 1] = sqk;
                }
            }
            // ---- consume norms for t (written NS barriers ago; different
            //      slot than this iteration's produce: (t+NS)&7 != t&7) ----
            float4 s0 = *(const float4*)&smn[t & 7][0];
            float4 s1 = *(const float4*)&smn[t & 7][4];
            float nq = s0.x + s0.z + s1.x + s1.z;
            float nk = s0.y + s0.w + s1.y + s1.w;
            float aq = ALPHA / (sqrtf(nq) + 1e-6f);
            float ak = ALPHA / (sqrtf(nk) + 1e-6f);
            // ---- EMA update ----
            u0 = om*u0 + aq*pq[j].x; u1 = om*u1 + aq*pq[j].y;
            u2 = om*u2 + aq*pq[j].z; u3 = om*u3 + aq*pq[j].w;
            v0 = om*v0 + ak*pk[j].x; v1 = om*v1 + ak*pk[j].y;
            v2 = om*v2 + ak*pk[j].z; v3 = om*v3 + ak*pk[j].w;
            if (t >= t0) {                        // wave-uniform
                // per-thread partials only; reduction deferred to post-loop
                pp[t - t0][tid][0] = u0*u0 + u1*u1 + u2*u2 + u3*u3;
                pp[t - t0][tid][1] = v0*pv[j].x + v1*pv[j].y + v2*pv[j].z + v3*pv[j].w;
                ushort4 us;
                us.x = f2bf(u0); us.y = f2bf(u1); us.z = f2bf(u2); us.w = f2bf(u3);
                *(ushort4*)(up + (size_t)t * D_) = us;
            }
            // ---- prefetch t+PF_ into slot j (clamped; dup loads harmless) ----
            int tf = t + PF_;
            int tc = tf < tend ? tf : tend - 1;
            size_t o2 = (size_t)tc * D_;
            pq[j] = *(const float4*)(qp + o2);
            pk[j] = *(const float4*)(kp + o2);
            if (tf >= t0) pv[j] = *(const float4*)(vp + o2);
        }
    }
    __syncthreads();
    // post-loop: reduce pp columns; wave w owns t = w, w+4, ...
    for (int tt = wave; tt < TB; tt += 4) {
        const float* row = &pp[tt][lane * 4][0];
        float4 r0 = *(const float4*)(row);
        float4 r1 = *(const float4*)(row + 4);
        float uu = r0.x + r0.z + r1.x + r1.z;
        float sd = r0.y + r0.w + r1.y + r1.w;
#pragma unroll
        for (int off = 32; off > 0; off >>= 1) {
            uu += __shfl_xor(uu, off, 64);
            sd += __shfl_xor(sd, off, 64);
        }
        if (lane == 0) {
            float nrm = RFAC * fabsf(sd) * sqrtf(uu);
            float n = fmaxf(nrm, 1e-6f);
            coef[b * S_ + t0 + tt] = GAMMA * RFAC * sd / (1.f + BETA * (n - 1.f));
        }
    }
}

// ---------------------------------------------------------------------------
// Kernel 3: out[m,n] = x[m,n] + coef[m] * sum_d U[m,d] * W[n,d]
// 128x128 tile, BK=64, 4 waves (2x2), double-buffered 64KB LDS -> 2
// blocks/CU, grid 1024. Counted vmcnt 2-deep pipeline; XOR chunk swizzle.
// Measured ~37us (~930 TF incl. x+out epilogue) — unchanged from R8/R9.
#define BM 128
#define BN 128
#define BK 64
#define NT (D_ / BK)   // 16 K-tiles

__global__ __launch_bounds__(256) void gemm_k(const unsigned short* __restrict__ A,   // M x K bf16
                                              const unsigned short* __restrict__ Bw,  // N x K bf16
                                              const float* __restrict__ coef,
                                              const float* __restrict__ x,
                                              float* __restrict__ out) {
    const int N = D_, K = D_;
    __shared__ unsigned short lds[2 * 2 * BM * BK];   // [buf][A|B], 64 KiB
    int bid = blockIdx.x;
    int swz = (bid & 7) * 128 + (bid >> 3);  // 1024 % 8 == 0: bijective XCD remap
    int tm = swz >> 3, tn = swz & 7;         // 128 M-tiles, 8 N-tiles
    int m0 = tm * BM, n0 = tn * BN;
    int tid = threadIdx.x;
    int lane = tid & 63;
    int wid = tid >> 6;
    int wr = wid >> 1, wc = wid & 1;         // 2x2 wave grid; wave tile 64x64
    int lr = lane & 15, lg = lane >> 4;

    f32x4_t acc[4][4];
#pragma unroll
    for (int i = 0; i < 4; ++i)
#pragma unroll
        for (int j = 0; j < 4; ++j)
            acc[i][j] = (f32x4_t){0.f, 0.f, 0.f, 0.f};

#define STAGE_MAT(buf, kt, isB)                                                       \
    {                                                                                 \
        const unsigned short* Gp =                                                    \
            ((isB) ? Bw + (size_t)n0 * K : A + (size_t)m0 * K) + (size_t)(kt) * BK;   \
        char* Lp = (char*)lds + (buf) * 32768 + (isB) * 16384;                        \
        _Pragma("unroll")                                                             \
        for (int i = 0; i < 4; ++i) {                                                 \
            int c = i * 256 + tid;                                                    \
            int row = c >> 3, cl = c & 7;                                             \
            int gc = cl ^ (row & 7);          /* pre-swizzled global chunk */         \
            __builtin_amdgcn_global_load_lds(                                         \
                (const __attribute__((address_space(1))) void*)(Gp + (size_t)row * K + gc * 8), \
                (__attribute__((address_space(3))) void*)(Lp + c * 16), 16, 0, 0);    \
        }                                                                             \
    }
#define STAGE_TILE(buf, kt) STAGE_MAT(buf, kt, 0) STAGE_MAT(buf, kt, 1)

    STAGE_TILE(0, 0);
    STAGE_TILE(1, 1);

    for (int t = 0; t < NT; ++t) {
        if (t == NT - 1) asm volatile("s_waitcnt vmcnt(0)" ::: "memory");
        else             asm volatile("s_waitcnt vmcnt(8)" ::: "memory");
        __builtin_amdgcn_s_barrier();
        const unsigned short* La = lds + (t & 1) * 16384;
        const unsigned short* Lb = La + 8192;
        bf16x8_t af[4][2], bf[4][2];
#pragma unroll
        for (int kkk = 0; kkk < 2; ++kkk) {
#pragma unroll
            for (int mi = 0; mi < 4; ++mi) {
                int row = wr * 64 + mi * 16 + lr;
                int ch = (kkk * 4 + lg) ^ (row & 7);
                af[mi][kkk] = *(const bf16x8_t*)(La + (row * 8 + ch) * 8);
            }
#pragma unroll
            for (int ni = 0; ni < 4; ++ni) {
                int row = wc * 64 + ni * 16 + lr;
                int ch = (kkk * 4 + lg) ^ (row & 7);
                bf[ni][kkk] = *(const bf16x8_t*)(Lb + (row * 8 + ch) * 8);
            }
        }
        asm volatile("s_waitcnt lgkmcnt(0)" ::: "memory");
        __builtin_amdgcn_sched_barrier(0);
        __builtin_amdgcn_s_setprio(1);
#pragma unroll
        for (int kkk = 0; kkk < 2; ++kkk)
#pragma unroll
            for (int mi = 0; mi < 4; ++mi)
#pragma unroll
                for (int ni = 0; ni < 4; ++ni)
                    acc[mi][ni] = __builtin_amdgcn_mfma_f32_16x16x32_bf16(
                        af[mi][kkk], bf[ni][kkk], acc[mi][ni], 0, 0, 0);
        __builtin_amdgcn_s_setprio(0);
        __builtin_amdgcn_s_barrier();
        if (t + 2 < NT) { STAGE_TILE((t & 1), t + 2); }
    }
#undef STAGE_TILE
#undef STAGE_MAT

#pragma unroll
    for (int mi = 0; mi < 4; ++mi) {
#pragma unroll
        for (int i = 0; i < 4; ++i) {
            int m = m0 + wr * 64 + mi * 16 + lg * 4 + i;
            float cf = coef[m];
#pragma unroll
            for (int ni = 0; ni < 4; ++ni) {
                int n = n0 + wc * 64 + ni * 16 + lr;
                size_t idx = (size_t)m * N + n;
                out[idx] = x[idx] + cf * acc[mi][ni][i];
            }
        }
    }
}

// ---------------------------------------------------------------------------
extern "C" void kernel_launch(void* const* d_in, const int* in_sizes, int n_in,
                              void* d_out, int out_size, void* d_ws, size_t ws_size,
                              hipStream_t stream) {
    const float* x  = (const float*)d_in[0];
    const float* q  = (const float*)d_in[1];
    const float* k  = (const float*)d_in[2];
    const float* vv = (const float*)d_in[3];
    const float* W  = (const float*)d_in[4];
    float* out = (float*)d_out;

    const size_t M = (size_t)B_ * S_;           // 16384
    char* ws = (char*)d_ws;
    unsigned short* Ub = (unsigned short*)ws;                      // 32MB
    unsigned short* Wb = (unsigned short*)(ws + M * D_ * 2);       // 2MB
    float* coef = (float*)(ws + M * D_ * 2 + (size_t)D_ * D_ * 2);
    size_t needed = M * D_ * 2 + (size_t)D_ * D_ * 2 + M * 4;
    if (ws_size < needed) return;  // fail visibly (output stays poisoned)

    wconv_k<<<dim3((D_ * D_) / 1024), dim3(256), 0, stream>>>(W, Wb);
    ema_fused_k<<<dim3(B_ * (S_ / TB)), dim3(256), 0, stream>>>(q, k, vv, Ub, coef);
    gemm_k<<<dim3((M / BM) * (D_ / BN)), dim3(256), 0, stream>>>(Ub, Wb, coef, x, out);
}